// Round 1
// 1536.323 us; speedup vs baseline: 1.0075x; 1.0075x over previous
//
#include <hip/hip_runtime.h>
#include <hip/hip_bf16.h>

// SSN soft superpixel clustering, MI355X (gfx950).
// x: [B=2, C=5, H=512, W=512] fp32; K=256 superpixels; 10 EM iterations.
// Output: soft assignment transposed [B, K, N] fp32 (512 MiB).
//
// Math: softmax_k(-(p2 + c2 - 2 dot)) == softmax_k(2 dot - c2)   (p2 drops).
// Precompute per-k table row[8] = {2*L*c0..2*L*c4, -L*||c||^2, 0, 0}, L=log2(e),
// so logit_for_exp2 = row[5] + sum_c row[c]*pix_c and aff = exp2(logit)/S.
//
// R1: phase B was LDS-issue-bound (6 scalar ds_read_b32 broadcasts per pixel
// per thread = 49k LDS insts/CU/step ~ 119 us/step). Restructured: waves split
// the pixel tile (128 px each), each lane owns 4 k's, pixel data read as
// f32x4 (6 ds_read_b128 per 4 px) -> 16x fewer LDS instructions; cross-wave
// combine via LDS partials overlaid on the dead pixel tile.

#define B_ 2
#define C_ 5
#define H_ 512
#define W_ 512
#define N_ (H_*W_)          // 262144
#define K_ 256
#define NITER_ 10
#define T_ 512              // pixels per step-kernel block
#define LOG2E 1.4426950408889634f

typedef float f32x8 __attribute__((ext_vector_type(8)));
typedef float f32x4 __attribute__((ext_vector_type(4)));

// ---------------------------------------------------------------------------
// Kernel 1: grid-init centers = 32x32 block means, written as scaled table.
// grid = B*K blocks x 256 threads.
__global__ __launch_bounds__(256) void init_centers(const float* __restrict__ x,
                                                    float* __restrict__ ctab) {
    int bk  = blockIdx.x;            // 0..511
    int b   = bk >> 8;
    int k   = bk & (K_ - 1);
    int gy  = k >> 4, gx = k & 15;   // 16x16 grid of 32x32 blocks
    int tid = threadIdx.x;

    float s[C_] = {0.f, 0.f, 0.f, 0.f, 0.f};
    for (int i = tid; i < 1024; i += 256) {          // 4 pixels per thread
        int py = i >> 5, px = i & 31;
        int n  = (gy * 32 + py) * W_ + gx * 32 + px;
        const float* xb = x + (size_t)b * C_ * N_ + n;
        #pragma unroll
        for (int c = 0; c < C_; c++) s[c] += xb[(size_t)c * N_];
    }
    // wave (64-lane) reduce, then cross-wave via LDS
    #pragma unroll
    for (int c = 0; c < C_; c++) {
        #pragma unroll
        for (int off = 32; off > 0; off >>= 1)
            s[c] += __shfl_down(s[c], off, 64);
    }
    __shared__ float wred[4][C_];
    int lane = tid & 63, wid = tid >> 6;
    if (lane == 0) {
        #pragma unroll
        for (int c = 0; c < C_; c++) wred[wid][c] = s[c];
    }
    __syncthreads();
    if (tid == 0) {
        float m[C_]; float c2 = 0.f;
        #pragma unroll
        for (int c = 0; c < C_; c++) {
            m[c] = (wred[0][c] + wred[1][c] + wred[2][c] + wred[3][c]) * (1.0f / 1024.0f);
            c2  += m[c] * m[c];
        }
        float* row = ctab + (size_t)(b * K_ + k) * 8;
        #pragma unroll
        for (int c = 0; c < C_; c++) row[c] = 2.0f * LOG2E * m[c];
        row[5] = -LOG2E * c2;
        row[6] = 0.f; row[7] = 0.f;
    }
}

// ---------------------------------------------------------------------------
// Kernel 2: one EM step.
// Phase A: per-pixel softmax denom (centers via wave-uniform scalar loads).
// Phase B: wave w owns pixels [w*128, w*128+128); lane owns 4 k's
// (k = lane + 64j). Pixel data read as f32x4 broadcasts (6 ds_read_b128 per
// 4 pixels instead of 24 ds_read_b32 per 4 pixels per thread before).
// Cross-wave partials combined in LDS (overlaid on the dead pixel tile),
// then 6 atomics per thread as before.
// grid = B * (N/T_) = 1024 blocks x 256 threads.
__global__ __launch_bounds__(256, 4) void step_kernel(const float* __restrict__ x,
                                                      const float* __restrict__ ctab,
                                                      float* __restrict__ acc) {
    __shared__ union SM {
        struct { float pl[C_][T_]; float rs[T_]; } s;   // 12.25 KB (phases A/B)
        float part[4][6][K_];                           // 24 KB (reduction)
    } sm;
    int bid = blockIdx.x;
    int b   = bid >> 9;                 // 512 blocks per batch
    int n0  = (bid & 511) * T_;
    int tid = threadIdx.x;

    const float* xb = x + (size_t)b * C_ * N_ + n0;
    #pragma unroll
    for (int c = 0; c < C_; c++) {
        sm.s.pl[c][tid]       = xb[(size_t)c * N_ + tid];
        sm.s.pl[c][tid + 256] = xb[(size_t)c * N_ + tid + 256];
    }
    __syncthreads();

    // ---- phase A: two pixels per thread share each center-table row ----
    float pa[C_], pb[C_];
    #pragma unroll
    for (int c = 0; c < C_; c++) { pa[c] = sm.s.pl[c][tid]; pb[c] = sm.s.pl[c][tid + 256]; }

    const f32x8* crow = (const f32x8*)(ctab + (size_t)b * K_ * 8);
    float S0 = 0.f, S1 = 0.f;
    #pragma unroll 8
    for (int k = 0; k < K_; k++) {
        f32x8 r = crow[k];               // wave-uniform -> s_load_dwordx8
        float l0 = r[5], l1 = r[5];
        l0 = fmaf(r[0], pa[0], l0);  l1 = fmaf(r[0], pb[0], l1);
        l0 = fmaf(r[1], pa[1], l0);  l1 = fmaf(r[1], pb[1], l1);
        l0 = fmaf(r[2], pa[2], l0);  l1 = fmaf(r[2], pb[2], l1);
        l0 = fmaf(r[3], pa[3], l0);  l1 = fmaf(r[3], pb[3], l1);
        l0 = fmaf(r[4], pa[4], l0);  l1 = fmaf(r[4], pb[4], l1);
        S0 += __builtin_amdgcn_exp2f(l0);
        S1 += __builtin_amdgcn_exp2f(l1);
    }
    sm.s.rs[tid]       = 1.0f / S0;
    sm.s.rs[tid + 256] = 1.0f / S1;
    __syncthreads();

    // ---- phase B: wave-split pixels, 4 k's per lane, f32x4 LDS reads ----
    int lane = tid & 63, wid = tid >> 6;

    float cc[4][6];                      // 4 center rows per lane
    #pragma unroll
    for (int j = 0; j < 4; j++) {
        const float* row = ctab + (size_t)(b * K_ + lane + 64 * j) * 8;
        f32x4 r0 = *(const f32x4*)row;
        f32x4 r1 = *(const f32x4*)(row + 4);
        cc[j][0] = r0[0]; cc[j][1] = r0[1]; cc[j][2] = r0[2];
        cc[j][3] = r0[3]; cc[j][4] = r1[0]; cc[j][5] = r1[1];
    }
    float av[4][6];
    #pragma unroll
    for (int j = 0; j < 4; j++)
        #pragma unroll
        for (int c = 0; c < 6; c++) av[j][c] = 0.f;

    int pbase = wid * 128;
    #pragma unroll 1
    for (int p = pbase; p < pbase + 128; p += 4) {
        f32x4 q0 = *(const f32x4*)&sm.s.pl[0][p];   // broadcast ds_read_b128
        f32x4 q1 = *(const f32x4*)&sm.s.pl[1][p];
        f32x4 q2 = *(const f32x4*)&sm.s.pl[2][p];
        f32x4 q3 = *(const f32x4*)&sm.s.pl[3][p];
        f32x4 q4 = *(const f32x4*)&sm.s.pl[4][p];
        f32x4 rr = *(const f32x4*)&sm.s.rs[p];
        #pragma unroll
        for (int u = 0; u < 4; u++) {
            #pragma unroll
            for (int j = 0; j < 4; j++) {
                float l = cc[j][5];
                l = fmaf(cc[j][0], q0[u], l);
                l = fmaf(cc[j][1], q1[u], l);
                l = fmaf(cc[j][2], q2[u], l);
                l = fmaf(cc[j][3], q3[u], l);
                l = fmaf(cc[j][4], q4[u], l);
                float af = __builtin_amdgcn_exp2f(l) * rr[u];
                av[j][5] += af;
                av[j][0] = fmaf(q0[u], af, av[j][0]);
                av[j][1] = fmaf(q1[u], af, av[j][1]);
                av[j][2] = fmaf(q2[u], af, av[j][2]);
                av[j][3] = fmaf(q3[u], af, av[j][3]);
                av[j][4] = fmaf(q4[u], af, av[j][4]);
            }
        }
    }

    __syncthreads();                     // pl/rs dead; reuse LDS as partials
    #pragma unroll
    for (int j = 0; j < 4; j++)
        #pragma unroll
        for (int c = 0; c < 6; c++)
            sm.part[wid][c][lane + 64 * j] = av[j][c];
    __syncthreads();

    float s0 = 0.f, s1 = 0.f, s2 = 0.f, s3 = 0.f, s4 = 0.f, sw = 0.f;
    #pragma unroll
    for (int w = 0; w < 4; w++) {
        s0 += sm.part[w][0][tid]; s1 += sm.part[w][1][tid];
        s2 += sm.part[w][2][tid]; s3 += sm.part[w][3][tid];
        s4 += sm.part[w][4][tid]; sw += sm.part[w][5][tid];
    }
    float* ab = acc + (size_t)b * 6 * K_ + tid;
    unsafeAtomicAdd(ab + 0 * K_, s0);   // native global_atomic_add_f32
    unsafeAtomicAdd(ab + 1 * K_, s1);
    unsafeAtomicAdd(ab + 2 * K_, s2);
    unsafeAtomicAdd(ab + 3 * K_, s3);
    unsafeAtomicAdd(ab + 4 * K_, s4);
    unsafeAtomicAdd(ab + 5 * K_, sw);
}

// ---------------------------------------------------------------------------
// Kernel 3: centers <- csum / (wsum + 1e-16), rewritten as scaled table.
// grid = B blocks x 256 threads.
__global__ __launch_bounds__(256) void update_centers(const float* __restrict__ acc,
                                                      float* __restrict__ ctab) {
    int b = blockIdx.x;
    int k = threadIdx.x;
    const float* ab = acc + (size_t)b * 6 * K_ + k;
    float w = ab[5 * K_] + 1e-16f;
    float m[C_]; float c2 = 0.f;
    #pragma unroll
    for (int c = 0; c < C_; c++) { m[c] = ab[(size_t)c * K_] / w; c2 += m[c] * m[c]; }
    float* row = ctab + (size_t)(b * K_ + k) * 8;
    #pragma unroll
    for (int c = 0; c < C_; c++) row[c] = 2.0f * LOG2E * m[c];
    row[5] = -LOG2E * c2;
    row[6] = 0.f; row[7] = 0.f;
}

// ---------------------------------------------------------------------------
// Kernel 4: final affinity, written transposed [B, K, N]. Pixel-per-lane so
// stores along n are coalesced. grid = B*N/256 blocks x 256 threads.
__global__ __launch_bounds__(256, 4) void final_kernel(const float* __restrict__ x,
                                                       const float* __restrict__ ctab,
                                                       float* __restrict__ out) {
    size_t gid = (size_t)blockIdx.x * 256 + threadIdx.x;   // 0..B*N-1
    int b = (int)(gid >> 18);                              // N_ == 2^18
    int n = (int)(gid & (size_t)(N_ - 1));

    const float* xb = x + (size_t)b * C_ * N_ + n;
    float p[C_];
    #pragma unroll
    for (int c = 0; c < C_; c++) p[c] = xb[(size_t)c * N_];

    const f32x8* crow = (const f32x8*)(ctab + (size_t)b * K_ * 8);
    float S = 0.f;
    #pragma unroll 8
    for (int k = 0; k < K_; k++) {
        f32x8 r = crow[k];
        float l = r[5];
        l = fmaf(r[0], p[0], l); l = fmaf(r[1], p[1], l); l = fmaf(r[2], p[2], l);
        l = fmaf(r[3], p[3], l); l = fmaf(r[4], p[4], l);
        S += __builtin_amdgcn_exp2f(l);
    }
    float rS = 1.0f / S;

    float* ob = out + (size_t)b * K_ * N_ + n;
    #pragma unroll 4
    for (int k = 0; k < K_; k++) {
        f32x8 r = crow[k];
        float l = r[5];
        l = fmaf(r[0], p[0], l); l = fmaf(r[1], p[1], l); l = fmaf(r[2], p[2], l);
        l = fmaf(r[3], p[3], l); l = fmaf(r[4], p[4], l);
        ob[(size_t)k * N_] = __builtin_amdgcn_exp2f(l) * rS;   // coalesced in n
    }
}

// ---------------------------------------------------------------------------
extern "C" void kernel_launch(void* const* d_in, const int* in_sizes, int n_in,
                              void* d_out, int out_size, void* d_ws, size_t ws_size,
                              hipStream_t stream) {
    const float* x = (const float*)d_in[0];
    // d_in[1] = nspix (=256), d_in[2] = n_iter (=10): fixed by setup_inputs,
    // compiled in as constants (device-side scalars can't be read during capture).
    float* out  = (float*)d_out;
    float* ctab = (float*)d_ws;                       // B*K*8 = 4096 floats
    float* acc  = ctab + (size_t)B_ * K_ * 8;         // NITER slots x B*6*K

    // ws is re-poisoned to 0xAA before every timed call: zero the accumulators.
    hipMemsetAsync(acc, 0, (size_t)NITER_ * B_ * 6 * K_ * sizeof(float), stream);

    init_centers<<<B_ * K_, 256, 0, stream>>>(x, ctab);
    for (int s = 0; s < NITER_; s++) {
        float* as = acc + (size_t)s * B_ * 6 * K_;
        step_kernel<<<B_ * (N_ / T_), 256, 0, stream>>>(x, ctab, as);
        update_centers<<<B_, 256, 0, stream>>>(as, ctab);
    }
    final_kernel<<<(B_ * N_) / 256, 256, 0, stream>>>(x, ctab, out);
}

// Round 2
// 1356.656 us; speedup vs baseline: 1.1409x; 1.1324x over previous
//
#include <hip/hip_runtime.h>
#include <hip/hip_bf16.h>

// SSN soft superpixel clustering, MI355X (gfx950).
// x: [B=2, C=5, H=512, W=512] fp32; K=256 superpixels; 10 EM iterations.
// Output: soft assignment transposed [B, K, N] fp32 (512 MiB).
//
// Math: softmax_k(-(p2 + c2 - 2 dot)) == softmax_k(2 dot - c2)   (p2 drops).
// Per-k row (exp2 form): crow[8] = {2*L*c0..2*L*c4, -L*||c||^2, 0, 0}, L=log2(e);
// pixel aug vector pix_aug[8] = {p0..p4, 1, 0, 0}; logit = dot(pix_aug, crow).
//
// R2: step kernel was VALU-bound (two dense contractions, ~3 GFLOP/step on the
// vector ALU ~ 34us/step issue + 2x exp2). Moved both GEMMs to MFMA
// (16x16x32 bf16) with fp32 accuracy via hi/lo bf16 compensation packed into
// the K=32 dim: A-quadrants [ph,pl,ph,pl] x B-quadrants [ch,ch,cl,cl] sum to
// (ph+pl)(ch+cl) in ONE mfma. exp2 now computed once per (n,k) (was 2x).
// GEMM2 (csum[c,k] = sum_n pix*aff, incl. wsum via the ones-channel) consumes
// aff through a 1KB/wave in-wave LDS transpose (80B rows, <=2-way conflicts).
// Waves are fully independent (no barrier until the epilogue reduce).

#define B_ 2
#define C_ 5
#define H_ 512
#define W_ 512
#define N_ (H_*W_)          // 262144
#define K_ 256
#define NITER_ 10
#define LOG2E 1.4426950408889634f

typedef float f32x8 __attribute__((ext_vector_type(8)));
typedef float f32x4 __attribute__((ext_vector_type(4)));
typedef short bf16x8 __attribute__((ext_vector_type(8)));
typedef unsigned int u32;
typedef u32 u32x4 __attribute__((ext_vector_type(4)));

// Truncation-based fp32 -> bf16 hi/lo split, packed as (lo16=a, hi16=b).
// hi exactly representable; a - hi exact (Sterbenz); residual ~2^-16 rel.
__device__ inline void split2(float a, float b, u32& hi, u32& lo) {
    u32 ua = __builtin_bit_cast(u32, a), ub = __builtin_bit_cast(u32, b);
    u32 ha = ua & 0xffff0000u, hb = ub & 0xffff0000u;
    hi = (ha >> 16) | hb;
    float la = a - __builtin_bit_cast(float, ha);
    float lb = b - __builtin_bit_cast(float, hb);
    lo = (__builtin_bit_cast(u32, la) >> 16) |
         (__builtin_bit_cast(u32, lb) & 0xffff0000u);
}

// ---------------------------------------------------------------------------
// Prolog A: pixaug[b][n][2][8] bf16 — pixel-major hi/lo split of aug vector.
// A1-fragment-ready: 16B = 8 bf16 channels (p0..p4, 1, 0, 0), hi then lo.
__global__ __launch_bounds__(256) void prep_pix(const float* __restrict__ x,
                                                u32* __restrict__ pixaug) {
    size_t i = (size_t)blockIdx.x * 256 + threadIdx.x;   // 0..B*N-1
    int b = (int)(i >> 18);
    int n = (int)(i & (size_t)(N_ - 1));
    const float* xb = x + (size_t)b * C_ * N_ + n;
    float p0 = xb[0], p1 = xb[(size_t)N_], p2 = xb[2*(size_t)N_];
    float p3 = xb[3*(size_t)N_], p4 = xb[4*(size_t)N_];
    u32 h01, l01, h23, l23, h45, l45;
    split2(p0, p1, h01, l01);
    split2(p2, p3, h23, l23);
    split2(p4, 1.0f, h45, l45);       // ones channel: hi16=0x3F80, lo=0
    u32x4* o = (u32x4*)pixaug + (i << 1);
    o[0] = (u32x4){h01, h23, h45, 0u};
    o[1] = (u32x4){l01, l23, l45, 0u};
}

// Prolog B: pixT[b][g][2][8c][8px] bf16 — channel-major per 8-pixel group.
// B2-fragment-ready: lane(c) reads 16B = 8 px of channel c (hi or lo).
__global__ __launch_bounds__(256) void prep_pixT(const float* __restrict__ x,
                                                 u32* __restrict__ pixT) {
    int gi = blockIdx.x * 256 + threadIdx.x;             // 0..B*(N/8)-1
    int b = gi >> 15;                                    // N/8 = 32768
    int g = gi & 32767;
    const float* xb = x + (size_t)b * C_ * N_ + (size_t)g * 8;
    u32 hw[8][4], lw[8][4];
    #pragma unroll
    for (int c = 0; c < 5; c++) {
        float pj[8];
        #pragma unroll
        for (int j = 0; j < 8; j++) pj[j] = xb[(size_t)c * N_ + j];
        #pragma unroll
        for (int w = 0; w < 4; w++) split2(pj[2*w], pj[2*w+1], hw[c][w], lw[c][w]);
    }
    #pragma unroll
    for (int w = 0; w < 4; w++) {
        hw[5][w] = 0x3F803F80u; lw[5][w] = 0u;           // ones channel
        hw[6][w] = 0u; lw[6][w] = 0u;
        hw[7][w] = 0u; lw[7][w] = 0u;
    }
    u32x4* o = (u32x4*)pixT + (size_t)gi * 16;
    #pragma unroll
    for (int c = 0; c < 8; c++) o[c]     = (u32x4){hw[c][0], hw[c][1], hw[c][2], hw[c][3]};
    #pragma unroll
    for (int c = 0; c < 8; c++) o[8 + c] = (u32x4){lw[c][0], lw[c][1], lw[c][2], lw[c][3]};
}

// ---------------------------------------------------------------------------
// Kernel 1: grid-init centers = 32x32 block means; writes fp32 table (for the
// final kernel) and bf16 hi/lo split table (for the MFMA step kernel).
__global__ __launch_bounds__(256) void init_centers(const float* __restrict__ x,
                                                    float* __restrict__ ctab,
                                                    u32* __restrict__ ctab_bf) {
    int bk  = blockIdx.x;            // 0..511
    int b   = bk >> 8;
    int k   = bk & (K_ - 1);
    int gy  = k >> 4, gx = k & 15;   // 16x16 grid of 32x32 blocks
    int tid = threadIdx.x;

    float s[C_] = {0.f, 0.f, 0.f, 0.f, 0.f};
    for (int i = tid; i < 1024; i += 256) {
        int py = i >> 5, px = i & 31;
        int n  = (gy * 32 + py) * W_ + gx * 32 + px;
        const float* xb = x + (size_t)b * C_ * N_ + n;
        #pragma unroll
        for (int c = 0; c < C_; c++) s[c] += xb[(size_t)c * N_];
    }
    #pragma unroll
    for (int c = 0; c < C_; c++) {
        #pragma unroll
        for (int off = 32; off > 0; off >>= 1)
            s[c] += __shfl_down(s[c], off, 64);
    }
    __shared__ float wred[4][C_];
    int lane = tid & 63, wid = tid >> 6;
    if (lane == 0) {
        #pragma unroll
        for (int c = 0; c < C_; c++) wred[wid][c] = s[c];
    }
    __syncthreads();
    if (tid == 0) {
        float m[C_]; float c2 = 0.f;
        #pragma unroll
        for (int c = 0; c < C_; c++) {
            m[c] = (wred[0][c] + wred[1][c] + wred[2][c] + wred[3][c]) * (1.0f / 1024.0f);
            c2  += m[c] * m[c];
        }
        float r[6];
        #pragma unroll
        for (int c = 0; c < C_; c++) r[c] = 2.0f * LOG2E * m[c];
        r[5] = -LOG2E * c2;
        float* row = ctab + (size_t)(b * K_ + k) * 8;
        #pragma unroll
        for (int c = 0; c < 6; c++) row[c] = r[c];
        row[6] = 0.f; row[7] = 0.f;
        u32 h01, l01, h23, l23, h45, l45;
        split2(r[0], r[1], h01, l01);
        split2(r[2], r[3], h23, l23);
        split2(r[4], r[5], h45, l45);
        u32x4* cbo = (u32x4*)ctab_bf + (((size_t)(b * K_ + k)) << 1);
        cbo[0] = (u32x4){h01, h23, h45, 0u};
        cbo[1] = (u32x4){l01, l23, l45, 0u};
    }
}

// ---------------------------------------------------------------------------
// Kernel 2: one EM step, MFMA formulation.
// Block = 4 waves x 128 px; wave is K-resident (all 256 k = 16 tiles).
// GEMM1: logits[16px x 16k] = mfma(A1=pix_aug hi/lo, B1=center hi/lo), K=32
//        compensated packing -> fp32-accurate logits.
// exp2 once per (n,k); denom = in-lane tile sum + 4x shfl_xor over k-cols.
// GEMM2: csum[16k x 16c] += mfma(A2=aff hi/lo, B2=pix_aug hi/lo), K=32 = 8 px
//        x 4 compensation groups; A2 built via 1KB/wave LDS transpose.
__global__ __launch_bounds__(256, 2) void step_kernel(
        const u32* __restrict__ pixaug, const u32* __restrict__ pixT,
        const u32* __restrict__ ctab_bf, float* __restrict__ acc) {
    __shared__ u32   tbuf[4][16][20];    // per-wave aff transpose, 80B rows (pad)
    __shared__ float part[4][6][K_];     // cross-wave csum partials

    int bid = blockIdx.x;
    int b   = bid >> 9;                  // 512 blocks per batch
    int n0  = (bid & 511) * 512;
    int tid = threadIdx.x;
    int lane = tid & 63, wid = tid >> 6;
    int kc = lane & 15, q = lane >> 4;
    int selA = q & 1;                    // [hi,lo,hi,lo] quadrant packing
    int selB = q >> 1;                   // [hi,hi,lo,lo] quadrant packing

    const u32x4* cbt = (const u32x4*)ctab_bf;
    const u32x4* pa  = (const u32x4*)pixaug;
    const u32x4* pt  = (const u32x4*)pixT;

    // K-resident center fragments: B1[t] covers k = 16t + kc
    bf16x8 B1[16];
    #pragma unroll
    for (int t = 0; t < 16; t++)
        B1[t] = __builtin_bit_cast(bf16x8,
                    cbt[(((size_t)b * K_ + 16 * t + kc) << 1) | (size_t)selB]);

    f32x4 acc2[16];
    #pragma unroll
    for (int t = 0; t < 16; t++) acc2[t] = (f32x4){0.f, 0.f, 0.f, 0.f};

    u32* tb = &tbuf[wid][0][0];
    bool cok = kc < 8;
    int  cw  = kc & 7;

    for (int s = 0; s < 8; s++) {
        int p0 = n0 + wid * 128 + 16 * s;
        // A1: rows = 16 px, k-slots [ph,pl,ph,pl]
        bf16x8 A1 = __builtin_bit_cast(bf16x8,
                        pa[(((size_t)b * N_ + p0 + kc) << 1) | (size_t)selA]);
        // B2 halves (px 0-7 / 8-15): cols = channel, k-slots [ph,pl,ph,pl]
        size_t gb = (size_t)b * (N_ >> 3) + (size_t)(p0 >> 3);
        u32x4 t0 = pt[gb * 16 + (size_t)selA * 8 + cw];
        u32x4 t1 = pt[(gb + 1) * 16 + (size_t)selA * 8 + cw];
        if (!cok) { t0 = (u32x4){0,0,0,0}; t1 = (u32x4){0,0,0,0}; }
        bf16x8 B2h0 = __builtin_bit_cast(bf16x8, t0);
        bf16x8 B2h1 = __builtin_bit_cast(bf16x8, t1);

        // ---- GEMM1: logits; D layout col=k(lane&15), row=px(4q+reg) ----
        f32x4 P[16];
        #pragma unroll
        for (int t = 0; t < 16; t++)
            P[t] = __builtin_amdgcn_mfma_f32_16x16x32_bf16(
                       A1, B1[t], (f32x4){0.f, 0.f, 0.f, 0.f}, 0, 0, 0);

        // ---- exp2 once; softmax denominators per px row ----
        f32x4 S = (f32x4){0.f, 0.f, 0.f, 0.f};
        #pragma unroll
        for (int t = 0; t < 16; t++) {
            #pragma unroll
            for (int r = 0; r < 4; r++) P[t][r] = __builtin_amdgcn_exp2f(P[t][r]);
            S += P[t];
        }
        #pragma unroll
        for (int r = 0; r < 4; r++) {
            float v = S[r];
            v += __shfl_xor(v, 1); v += __shfl_xor(v, 2);
            v += __shfl_xor(v, 4); v += __shfl_xor(v, 8);
            S[r] = 1.0f / v;                 // reciprocal denom
        }

        // ---- per k-tile: aff, hi/lo split, LDS transpose, GEMM2 ----
        #pragma unroll
        for (int t = 0; t < 16; t++) {
            f32x4 a = P[t] * S;              // normalized affinities (4 px)
            u32 ah01, al01, ah23, al23;
            split2(a[0], a[1], ah01, al01);
            split2(a[2], a[3], ah23, al23);
            // row = k-col (kc), section q holds px 4q..4q+3: [ah01 ah23 al01 al23]
            *(u32x4*)&tbuf[wid][kc][q * 4] = (u32x4){ah01, ah23, al01, al23};
            // read back transposed: lane row m = kc, [ah,ah,al,al] by selB
            {
                int wb = kc * 20 + 2 * selB;           // half 0: px 0-7
                u32x4 aw = {tb[wb], tb[wb + 1], tb[wb + 4], tb[wb + 5]};
                bf16x8 A2 = __builtin_bit_cast(bf16x8, aw);
                acc2[t] = __builtin_amdgcn_mfma_f32_16x16x32_bf16(
                              A2, B2h0, acc2[t], 0, 0, 0);
            }
            {
                int wb = kc * 20 + 8 + 2 * selB;       // half 1: px 8-15
                u32x4 aw = {tb[wb], tb[wb + 1], tb[wb + 4], tb[wb + 5]};
                bf16x8 A2 = __builtin_bit_cast(bf16x8, aw);
                acc2[t] = __builtin_amdgcn_mfma_f32_16x16x32_bf16(
                              A2, B2h1, acc2[t], 0, 0, 0);
            }
        }
    }

    // ---- epilogue: cross-wave reduce via LDS, then 6 atomics/thread ----
    // D2 layout: col = c (lane&15), row = k-in-tile (4q+reg)
    if (kc < 6) {
        #pragma unroll
        for (int t = 0; t < 16; t++)
            #pragma unroll
            for (int r = 0; r < 4; r++)
                part[wid][kc][16 * t + 4 * q + r] = acc2[t][r];
    }
    __syncthreads();
    float* ab = acc + (size_t)b * 6 * K_ + tid;
    #pragma unroll
    for (int c = 0; c < 6; c++) {
        float v = part[0][c][tid] + part[1][c][tid]
                + part[2][c][tid] + part[3][c][tid];
        unsafeAtomicAdd(ab + (size_t)c * K_, v);   // native global_atomic_add_f32
    }
}

// ---------------------------------------------------------------------------
// Kernel 3: centers <- csum / (wsum + 1e-16); writes fp32 + bf16 split tables.
__global__ __launch_bounds__(256) void update_centers(const float* __restrict__ acc,
                                                      float* __restrict__ ctab,
                                                      u32* __restrict__ ctab_bf) {
    int b = blockIdx.x;
    int k = threadIdx.x;
    const float* ab = acc + (size_t)b * 6 * K_ + k;
    float w = ab[5 * K_] + 1e-16f;
    float m[C_]; float c2 = 0.f;
    #pragma unroll
    for (int c = 0; c < C_; c++) { m[c] = ab[(size_t)c * K_] / w; c2 += m[c] * m[c]; }
    float r[6];
    #pragma unroll
    for (int c = 0; c < C_; c++) r[c] = 2.0f * LOG2E * m[c];
    r[5] = -LOG2E * c2;
    float* row = ctab + (size_t)(b * K_ + k) * 8;
    #pragma unroll
    for (int c = 0; c < 6; c++) row[c] = r[c];
    row[6] = 0.f; row[7] = 0.f;
    u32 h01, l01, h23, l23, h45, l45;
    split2(r[0], r[1], h01, l01);
    split2(r[2], r[3], h23, l23);
    split2(r[4], r[5], h45, l45);
    u32x4* cbo = (u32x4*)ctab_bf + (((size_t)(b * K_ + k)) << 1);
    cbo[0] = (u32x4){h01, h23, h45, 0u};
    cbo[1] = (u32x4){l01, l23, l45, 0u};
}

// ---------------------------------------------------------------------------
// Kernel 4: final affinity, written transposed [B, K, N]. Pixel-per-lane so
// stores along n are coalesced. grid = B*N/256 blocks x 256 threads.
__global__ __launch_bounds__(256, 4) void final_kernel(const float* __restrict__ x,
                                                       const float* __restrict__ ctab,
                                                       float* __restrict__ out) {
    size_t gid = (size_t)blockIdx.x * 256 + threadIdx.x;   // 0..B*N-1
    int b = (int)(gid >> 18);                              // N_ == 2^18
    int n = (int)(gid & (size_t)(N_ - 1));

    const float* xb = x + (size_t)b * C_ * N_ + n;
    float p[C_];
    #pragma unroll
    for (int c = 0; c < C_; c++) p[c] = xb[(size_t)c * N_];

    const f32x8* crow = (const f32x8*)(ctab + (size_t)b * K_ * 8);
    float S = 0.f;
    #pragma unroll 8
    for (int k = 0; k < K_; k++) {
        f32x8 r = crow[k];
        float l = r[5];
        l = fmaf(r[0], p[0], l); l = fmaf(r[1], p[1], l); l = fmaf(r[2], p[2], l);
        l = fmaf(r[3], p[3], l); l = fmaf(r[4], p[4], l);
        S += __builtin_amdgcn_exp2f(l);
    }
    float rS = 1.0f / S;

    float* ob = out + (size_t)b * K_ * N_ + n;
    #pragma unroll 4
    for (int k = 0; k < K_; k++) {
        f32x8 r = crow[k];
        float l = r[5];
        l = fmaf(r[0], p[0], l); l = fmaf(r[1], p[1], l); l = fmaf(r[2], p[2], l);
        l = fmaf(r[3], p[3], l); l = fmaf(r[4], p[4], l);
        ob[(size_t)k * N_] = __builtin_amdgcn_exp2f(l) * rS;   // coalesced in n
    }
}

// ---------------------------------------------------------------------------
extern "C" void kernel_launch(void* const* d_in, const int* in_sizes, int n_in,
                              void* d_out, int out_size, void* d_ws, size_t ws_size,
                              hipStream_t stream) {
    const float* x = (const float*)d_in[0];
    // d_in[1] = nspix (=256), d_in[2] = n_iter (=10): fixed by setup_inputs,
    // compiled in as constants (device-side scalars can't be read during capture).
    float* out  = (float*)d_out;
    float* ctab = (float*)d_ws;                         // B*K*8 = 4096 f
    float* acc  = ctab + 4096;                          // NITER x B*6*K = 30720 f
    u32*  ctab_bf = (u32*)(acc + (size_t)NITER_ * B_ * 6 * K_);   // 4096 u32
    u32*  pixaug  = ctab_bf + 4096;                     // B*N*8   u32 (16 MB)
    u32*  pixT    = pixaug + (size_t)B_ * N_ * 8;       // B*(N/8)*64 u32 (16 MB)

    // ws is re-poisoned before every timed call: zero the accumulators.
    hipMemsetAsync(acc, 0, (size_t)NITER_ * B_ * 6 * K_ * sizeof(float), stream);

    prep_pix<<<(B_ * N_) / 256, 256, 0, stream>>>(x, pixaug);
    prep_pixT<<<(B_ * (N_ / 8)) / 256, 256, 0, stream>>>(x, pixT);
    init_centers<<<B_ * K_, 256, 0, stream>>>(x, ctab, ctab_bf);
    for (int s = 0; s < NITER_; s++) {
        float* as = acc + (size_t)s * B_ * 6 * K_;
        step_kernel<<<B_ * (N_ / 512), 256, 0, stream>>>(pixaug, pixT, ctab_bf, as);
        update_centers<<<B_, 256, 0, stream>>>(as, ctab, ctab_bf);
    }
    final_kernel<<<(B_ * N_) / 256, 256, 0, stream>>>(x, ctab, out);
}